// Round 3
// baseline (2157.876 us; speedup 1.0000x reference)
//
#include <hip/hip_runtime.h>
#include <hip/hip_bf16.h>

typedef unsigned short u16;
typedef unsigned int u32;

__device__ __forceinline__ float bf2f(u16 h) { return __uint_as_float(((u32)h) << 16); }
__device__ __forceinline__ u16 f2bf(float f) {
    u32 u = __float_as_uint(f);
    u32 r = u + 0x7FFFu + ((u >> 16) & 1u);   // round-to-nearest-even
    return (u16)(r >> 16);
}
// monotone float->uint map for atomic max; key 0 is reserved "empty" (decodes from no writes -> 0.0)
__device__ __forceinline__ u32 fkey(float f) {
    u32 u = __float_as_uint(f);
    return ((int)u < 0) ? ~u : (u | 0x80000000u);
}
__device__ __forceinline__ float fdec(u32 k) {
    u32 u = (k & 0x80000000u) ? (k & 0x7FFFFFFFu) : ~k;
    return __uint_as_float(u);
}
__device__ __forceinline__ void unpack8(const u16* p, float* b) {
    uint4 v = *(const uint4*)p;
    b[0] = bf2f((u16)(v.x & 0xFFFF)); b[1] = bf2f((u16)(v.x >> 16));
    b[2] = bf2f((u16)(v.y & 0xFFFF)); b[3] = bf2f((u16)(v.y >> 16));
    b[4] = bf2f((u16)(v.z & 0xFFFF)); b[5] = bf2f((u16)(v.z >> 16));
    b[6] = bf2f((u16)(v.w & 0xFFFF)); b[7] = bf2f((u16)(v.w >> 16));
}
template<int BF16>
__device__ __forceinline__ float LD(const void* p, long i) {
    if constexpr (BF16) return bf2f(((const u16*)p)[i]);
    else return ((const float*)p)[i];
}
// load 8 consecutive weights (col-contig) from GLOBAL, either dtype
template<int BF16>
__device__ __forceinline__ void ld8w(const void* w, long off, float* b) {
    if constexpr (BF16) {
        unpack8((const u16*)w + off, b);
    } else {
        const float4* p = (const float4*)((const float*)w + off);
        float4 v0 = p[0], v1 = p[1];
        b[0] = v0.x; b[1] = v0.y; b[2] = v0.z; b[3] = v0.w;
        b[4] = v1.x; b[5] = v1.y; b[6] = v1.z; b[7] = v1.w;
    }
}

// -------- detector: flags[0]=1 if floats are bf16; flags[1]=1 if edge_index is int64 --------
__global__ void k_detect(const u32* __restrict__ x, const u32* __restrict__ ei, u32* __restrict__ flags) {
    if (threadIdx.x == 0 && blockIdx.x == 0) {
        int c = 0;
        for (int i = 0; i < 256; i++) {
            u32 e = (x[i] >> 7) & 0xFF;          // exponent field of low u16 if bf16-packed
            if (e >= 96 && e <= 160) c++;
        }
        flags[0] = (c >= 192) ? 1u : 0u;
        int z = 0;
        for (int i = 0; i < 64; i++) if (ei[2 * i + 1] == 0u) z++;   // int64 high words
        flags[1] = (z >= 48) ? 1u : 0u;
    }
}

__global__ void k_init(u32* __restrict__ p, int n) {
    for (int i = blockIdx.x * blockDim.x + threadIdx.x; i < n; i += gridDim.x * blockDim.x)
        p[i] = 0u;
}

// -------- K1: delta = mlp_h(x)  (96 -> 64 relu -> 3), f32 out.  LDS ~25.6 KB --------
template<int BF16>
__global__ void k_delta(const void* __restrict__ x,
                        const void* __restrict__ hw0, const void* __restrict__ hb0,
                        const void* __restrict__ hw1, const void* __restrict__ hb1,
                        float* __restrict__ delta, const u32* __restrict__ flags, int N)
{
    if (flags[0] != (u32)BF16) return;
    __shared__ float w0[96 * 64];
    __shared__ float b0[64];
    __shared__ float w1[64 * 3];
    __shared__ float b1[3];
    int tid = threadIdx.x;
    for (int i = tid; i < 96 * 64; i += 256) w0[i] = LD<BF16>(hw0, i);
    if (tid < 64) b0[tid] = LD<BF16>(hb0, tid);
    if (tid < 64 * 3) w1[tid] = LD<BF16>(hw1, tid);
    if (tid < 3) b1[tid] = LD<BF16>(hb1, tid);
    __syncthreads();
    int n = blockIdx.x * 256 + tid;
    if (n >= N) return;
    float acc[64];
#pragma unroll
    for (int j = 0; j < 64; j++) acc[j] = b0[j];
    if constexpr (BF16) {
        const u32* xr = (const u32*)x + (long)n * 48;
        for (int kk = 0; kk < 48; kk++) {
            u32 p = xr[kk];
            float a0 = bf2f((u16)(p & 0xFFFF));
            float a1 = bf2f((u16)(p >> 16));
            const float* wr0 = &w0[(2 * kk) * 64];
            const float* wr1 = &w0[(2 * kk + 1) * 64];
#pragma unroll
            for (int j = 0; j < 64; j++) acc[j] += a0 * wr0[j] + a1 * wr1[j];
        }
    } else {
        const float* xr = (const float*)x + (long)n * 96;
        for (int k = 0; k < 96; k++) {
            float a0 = xr[k];
            const float* wr = &w0[k * 64];
#pragma unroll
            for (int j = 0; j < 64; j++) acc[j] += a0 * wr[j];
        }
    }
    float d0 = b1[0], d1 = b1[1], d2 = b1[2];
#pragma unroll
    for (int j = 0; j < 64; j++) {
        float h = fmaxf(acc[j], 0.f);
        d0 += h * w1[j * 3 + 0];
        d1 += h * w1[j * 3 + 1];
        d2 += h * w1[j * 3 + 2];
    }
    delta[(long)n * 3 + 0] = d0; delta[(long)n * 3 + 1] = d1; delta[(long)n * 3 + 2] = d2;
}

// -------- K2: edge MLP (99 -> 128 relu -> 96) + atomic segment-max.  LDS ~34.8 KB --------
#define ET 16
template<int BF16>
__global__ void k_edge(const void* __restrict__ x, const void* __restrict__ pos,
                       const void* __restrict__ ei, const float* __restrict__ delta,
                       const void* __restrict__ fw0, const void* __restrict__ fb0,
                       const void* __restrict__ fw1, const void* __restrict__ fb1,
                       const u32* __restrict__ flags, u32* __restrict__ aggKey, int nE, int N)
{
    if (flags[0] != (u32)BF16) return;
    u32 i64f = flags[1];
    __shared__ __align__(16) u16 w0[99 * 128];   // [k][n], bf16
    __shared__ float b0[128];
    __shared__ float b1[96];
    __shared__ float buf[ET * 132];              // union: ein (99 wide) then h (128 wide)
    __shared__ int dstS[ET];
    int tid = threadIdx.x;
    if constexpr (BF16) {
        for (int i = tid; i < 99 * 128 / 2; i += 256) ((u32*)w0)[i] = ((const u32*)fw0)[i];
    } else {
        for (int i = tid; i < 99 * 128; i += 256) w0[i] = f2bf(((const float*)fw0)[i]);
    }
    if (tid < 128) b0[tid] = LD<BF16>(fb0, tid);
    if (tid < 96)  b1[tid] = LD<BF16>(fb1, tid);
    __syncthreads();

    const u32* e32 = (const u32*)ei;
    int ntile = nE / ET;   // 800000/16 = 50000, exact
    for (int t = blockIdx.x; t < ntile; t += gridDim.x) {
        { // stage 16 edges: buf[el] = [rel(3), x_src(96)]
            int el = tid >> 4;         // 0..15
            int g = tid & 15;          // 0..15, each loads 6 feats
            long E = (long)t * ET + el;
            int src, dst;
            if (i64f) { src = (int)e32[2 * E]; dst = (int)e32[2 * ((long)nE + E)]; }
            else      { src = (int)e32[E];     dst = (int)e32[(long)nE + E]; }
            src = min(max(src, 0), N - 1);
            dst = min(max(dst, 0), N - 1);
            if (g == 0) {
                dstS[el] = dst;
#pragma unroll
                for (int c = 0; c < 3; c++) {
                    buf[el * 132 + c] = LD<BF16>(pos, (long)src * 3 + c)
                                      - LD<BF16>(pos, (long)dst * 3 + c)
                                      + delta[(long)dst * 3 + c];
                }
            }
            if constexpr (BF16) {
                const u32* xr = (const u32*)x + (long)src * 48 + g * 3;
#pragma unroll
                for (int q = 0; q < 3; q++) {
                    u32 p = xr[q];
                    buf[el * 132 + 3 + g * 6 + 2 * q]     = bf2f((u16)(p & 0xFFFF));
                    buf[el * 132 + 3 + g * 6 + 2 * q + 1] = bf2f((u16)(p >> 16));
                }
            } else {
                const float* xr = (const float*)x + (long)src * 96 + g * 6;
#pragma unroll
                for (int q = 0; q < 6; q++) buf[el * 132 + 3 + g * 6 + q] = xr[q];
            }
        }
        __syncthreads();
        // GEMM1: h = relu(ein @ w0 + b0), M=16 K=99 N=128; 1 edge x 8 cols / thread
        {
            int tx = tid & 15;
            int ty = tid >> 4;
            float acc[8];
#pragma unroll
            for (int c = 0; c < 8; c++) acc[c] = 0.f;
            const float* e0 = &buf[ty * 132];
            for (int k = 0; k < 99; k++) {
                float a0 = e0[k];
                float b[8];
                unpack8(&w0[k * 128 + tx * 8], b);
#pragma unroll
                for (int c = 0; c < 8; c++) acc[c] += a0 * b[c];
            }
            __syncthreads();   // all ein reads done; buf reusable
#pragma unroll
            for (int c = 0; c < 8; c++) {
                int col = tx * 8 + c;
                buf[ty * 132 + col] = fmaxf(acc[c] + b0[col], 0.f);
            }
        }
        __syncthreads();
        // GEMM2: e2 = h @ w1 + b1, M=16 K=128 N=96; w1 straight from global (24KB, L1-resident)
        if (tid < 192) {
            int tx = tid % 12;
            int ty = tid / 12;
            float acc[8];
#pragma unroll
            for (int c = 0; c < 8; c++) acc[c] = 0.f;
            const float* h0 = &buf[ty * 132];
            for (int k = 0; k < 128; k++) {
                float a0 = h0[k];
                float b[8];
                ld8w<BF16>(fw1, (long)k * 96 + tx * 8, b);
#pragma unroll
                for (int c = 0; c < 8; c++) acc[c] += a0 * b[c];
            }
            int d0 = dstS[ty];
#pragma unroll
            for (int c = 0; c < 8; c++) {
                int col = tx * 8 + c;
                atomicMax(&aggKey[(size_t)d0 * 96 + col], fkey(acc[c] + b1[col]));
            }
        }
        __syncthreads();
    }
}

// -------- K3: out = x + mlp_g(agg)  (96 -> 128 relu -> 96).  LDS ~34 KB --------
template<int BF16>
__global__ void k_node(const void* __restrict__ x, const u32* __restrict__ aggKey,
                       const void* __restrict__ gw0, const void* __restrict__ gb0,
                       const void* __restrict__ gw1, const void* __restrict__ gb1,
                       void* __restrict__ out, const u32* __restrict__ flags, int N)
{
    if (flags[0] != (u32)BF16) return;
    __shared__ __align__(16) u16 w0[96 * 128];
    __shared__ float b0[128];
    __shared__ float b1[96];
    __shared__ float buf[16 * 132];
    int tid = threadIdx.x;
    if constexpr (BF16) {
        for (int i = tid; i < 96 * 128 / 2; i += 256) ((u32*)w0)[i] = ((const u32*)gw0)[i];
    } else {
        for (int i = tid; i < 96 * 128; i += 256) w0[i] = f2bf(((const float*)gw0)[i]);
    }
    if (tid < 128) b0[tid] = LD<BF16>(gb0, tid);
    if (tid < 96)  b1[tid] = LD<BF16>(gb1, tid);
    __syncthreads();

    int ntile = (N + 15) / 16;   // 3125, exact
    for (int t = blockIdx.x; t < ntile; t += gridDim.x) {
        { // stage: decode agg keys (0 == empty segment -> 0.0)
            int nl = tid >> 4, g = tid & 15;
            int n = t * 16 + nl;
            if (n < N) {
                const u32* ar = aggKey + (size_t)n * 96 + g * 6;
#pragma unroll
                for (int q = 0; q < 6; q++) {
                    u32 k2 = ar[q];
                    buf[nl * 132 + g * 6 + q] = (k2 == 0u) ? 0.f : fdec(k2);
                }
            } else {
#pragma unroll
                for (int q = 0; q < 6; q++) buf[nl * 132 + g * 6 + q] = 0.f;
            }
        }
        __syncthreads();
        // GEMM1: h = relu(agg @ w0 + b0), K=96 N=128
        {
            int tx = tid & 15;
            int ty = tid >> 4;
            float acc[8];
#pragma unroll
            for (int c = 0; c < 8; c++) acc[c] = 0.f;
            const float* e0 = &buf[ty * 132];
            for (int k = 0; k < 96; k++) {
                float a0 = e0[k];
                float b[8];
                unpack8(&w0[k * 128 + tx * 8], b);
#pragma unroll
                for (int c = 0; c < 8; c++) acc[c] += a0 * b[c];
            }
            __syncthreads();
#pragma unroll
            for (int c = 0; c < 8; c++) {
                int col = tx * 8 + c;
                buf[ty * 132 + col] = fmaxf(acc[c] + b0[col], 0.f);
            }
        }
        __syncthreads();
        // GEMM2 + residual + store, K=128 N=96; w1 from global
        if (tid < 192) {
            int tx = tid % 12;
            int ty = tid / 12;
            float acc[8];
#pragma unroll
            for (int c = 0; c < 8; c++) acc[c] = 0.f;
            const float* h0 = &buf[ty * 132];
            for (int k = 0; k < 128; k++) {
                float a0 = h0[k];
                float b[8];
                ld8w<BF16>(gw1, (long)k * 96 + tx * 8, b);
#pragma unroll
                for (int c = 0; c < 8; c++) acc[c] += a0 * b[c];
            }
            int n = t * 16 + ty;
            if (n < N) {
                if constexpr (BF16) {
                    float xv[8];
                    unpack8((const u16*)x + (size_t)n * 96 + tx * 8, xv);
                    u32 o[4];
#pragma unroll
                    for (int c = 0; c < 4; c++) {
                        u16 lo = f2bf(xv[2 * c] + acc[2 * c] + b1[tx * 8 + 2 * c]);
                        u16 hi = f2bf(xv[2 * c + 1] + acc[2 * c + 1] + b1[tx * 8 + 2 * c + 1]);
                        o[c] = (u32)lo | ((u32)hi << 16);
                    }
                    *(uint4*)((u16*)out + (size_t)n * 96 + tx * 8) = make_uint4(o[0], o[1], o[2], o[3]);
                } else {
                    const float* xr = (const float*)x + (size_t)n * 96 + tx * 8;
                    float* orow = (float*)out + (size_t)n * 96 + tx * 8;
#pragma unroll
                    for (int c = 0; c < 8; c++) orow[c] = xr[c] + acc[c] + b1[tx * 8 + c];
                }
            }
        }
        __syncthreads();
    }
}

extern "C" void kernel_launch(void* const* d_in, const int* in_sizes, int n_in,
                              void* d_out, int out_size, void* d_ws, size_t ws_size,
                              hipStream_t stream) {
    const void* x   = d_in[0];
    const void* pos = d_in[1];
    const void* ei  = d_in[2];
    const void* hw0 = d_in[3];
    const void* hb0 = d_in[4];
    const void* hw1 = d_in[5];
    const void* hb1 = d_in[6];
    const void* fw0 = d_in[7];
    const void* fb0 = d_in[8];
    const void* fw1 = d_in[9];
    const void* fb1 = d_in[10];
    const void* gw0 = d_in[11];
    const void* gb0 = d_in[12];
    const void* gw1 = d_in[13];
    const void* gb1 = d_in[14];

    int N  = in_sizes[0] / 96;   // 50000
    int nE = in_sizes[2] / 2;    // 800000

    u32*   flags  = (u32*)d_ws;                            // 2 u32
    float* delta  = (float*)((char*)d_ws + 256);           // N*3 f32 (600 KB)
    u32*   aggKey = (u32*)((char*)d_ws + (1 << 20));       // N*96 u32 (19.2 MB)

    k_detect<<<1, 64, 0, stream>>>((const u32*)x, (const u32*)ei, flags);
    k_init<<<1024, 256, 0, stream>>>(aggKey, N * 96);
    k_delta<1><<<(N + 255) / 256, 256, 0, stream>>>(x, hw0, hb0, hw1, hb1, delta, flags, N);
    k_delta<0><<<(N + 255) / 256, 256, 0, stream>>>(x, hw0, hb0, hw1, hb1, delta, flags, N);
    k_edge<1><<<1920, 256, 0, stream>>>(x, pos, ei, delta, fw0, fb0, fw1, fb1, flags, aggKey, nE, N);
    k_edge<0><<<1920, 256, 0, stream>>>(x, pos, ei, delta, fw0, fb0, fw1, fb1, flags, aggKey, nE, N);
    k_node<1><<<960, 256, 0, stream>>>(x, aggKey, gw0, gb0, gw1, gb1, d_out, flags, N);
    k_node<0><<<960, 256, 0, stream>>>(x, aggKey, gw0, gb0, gw1, gb1, d_out, flags, N);
}